// Round 8
// baseline (2037.597 us; speedup 1.0000x reference)
//
#include <hip/hip_runtime.h>
#include <hip/hip_fp16.h>

// N=1024, F=22, T=1000, H=64, gates 4H=256
// R18: timestep-batched FORWARD projections. R13..R17 showed the tick is
// insensitive to scheduling; the invariant cost is 44 MFMA/SIMD/tick (854cy).
// The M=16 rows carry only 4 batches (4x redundant). The fwd half
// (Wih.h_lower) is a pure linear map -> batch 4 TIMESTEPS into M=16 =
// 4 batches x 4 timesteps, computed once per 4 ticks:
//   L1/L2: fwd 16 -> 8 MFMA / 4 ticks (amortized 2/tick) + rec 8/tick = 10
//   per-SIMD: 12(L0) + 10 + 10 = 32 MFMA/tick (was 44) -> floor 621cy.
// Batched acc rows=(t',b); gates need batch-replicated -> in-register 4x4
// transpose across lane-groups (XOR16/XOR32 ds_bpermute butterfly, proven:
// B[q][r] = M[r][q]); after transpose the per-tick fwd term is a statically
// indexed reg (period-8 unroll). Bias rides in fwd C-init.
// Lags: L0 t=tau, L1 t=tau-6, L2 t=tau-12.
// L1 batch at tau==0 mod 4 covers t'=[tau-4,tau-1] (h0 ages 1-4; rec margin 2-5)
// L2 batch at tau==2 mod 4 covers t'=[tau-10,tau-7] (h1 ages 1-4; margin 2-5)
// Ring-8 audit: in1 c0..63 h0(t)@slot t&7 (wr by L0 @t, fwd-read age<=4);
//   in1 c64..127 h1(t)@slot (t+1)&7 (wr @t+6, rec-read age 1);
//   in2 c0..63 h1(t)@slot t&7 (wr @t+6, fwd-read age<=4, overwrite @t+14>t+10);
//   in2 c64..127 h2(t)@slot (t+1)&7 (wr @t+12, rec-read age 1).
//   All producer->consumer edges >=1 barrier; same-slot writes col-disjoint.
// Windows: L1 batch s=0->W0 (consumed s=2..5, ri=(s+2)&3), s=4->W1 (s=6..1);
//          L2 batch s=2->W0 (consumed s=4..7, ri=s&3),     s=6->W1 (s=0..3).
// Guards: L1 batch 4<=tau<=1000; L1 rec 6<=tau<=1005. L2 batch 10<=tau<=1006;
//   L2 rec 12<=tau<=1011 (final h2 -> fcA at tau=1011). Loop 127*8=1016 ticks,
//   1 barrier each, uniform for all 14 waves.
// 896 thr = 14 waves: 0-3 L2, 4-7 L1, 8-11 L0, 12-13 stager.
#define TT 1000
#define FF 22
#define HH 64
#define BB 4
#define NBLK 256
#define S0 112
#define S1 144
#define SL0 (4 * S0)
#define SL1 (4 * S1)

typedef _Float16 half8 __attribute__((ext_vector_type(8)));
typedef float float4v __attribute__((ext_vector_type(4)));

__device__ __forceinline__ float sel4(const float4v a, int q) {
    float lo = (q & 2) ? a[2] : a[0];
    float hi = (q & 2) ? a[3] : a[1];
    return (q & 1) ? hi : lo;
}

// Fused LSTM gate math: 5 exp + 2 rcp (R13, verified absmax 2.44e-4).
__device__ __forceinline__ float gate_fused(const float z[4], float& c) {
    float e0 = __expf(-z[0]);
    float e1 = __expf(-z[1]);
    float e2 = __expf(2.0f * z[2]);
    float d1 = 1.0f + e1;
    float d2 = (1.0f + e0) * (1.0f + e2);
    float r  = __builtin_amdgcn_rcpf(d1 * d2);
    float f  = d2 * r;
    float ig = (e2 - 1.0f) * (d1 * r);
    float cc = __builtin_fmaf(f, c, ig);
    c = cc;
    float e3 = __expf(-z[3]);
    float e4 = __expf(2.0f * cc);
    float r2 = __builtin_amdgcn_rcpf((1.0f + e3) * (1.0f + e4));
    return (e4 - 1.0f) * r2;
}

__device__ __forceinline__ float bperm(int idx4, float v) {
    return __int_as_float(__builtin_amdgcn_ds_bpermute(idx4, __float_as_int(v)));
}

// 4x4 transpose across lane-groups (stride-16): W[q][r] = F[r][q].
// Stage1 (XOR16, swap iff (q^r)&1), Stage2 (XOR32, swap iff (q^r)&2).
__device__ __forceinline__ void transp4(float4v& w, float4v f, bool qo, bool qh,
                                        int i16, int i32) {
    float s10 = bperm(i16, f[1]);
    float s11 = bperm(i16, f[0]);
    float s12 = bperm(i16, f[3]);
    float s13 = bperm(i16, f[2]);
    float b0 = qo ? s10 : f[0];
    float b1 = qo ? f[1] : s11;
    float b2 = qo ? s12 : f[2];
    float b3 = qo ? f[3] : s13;
    float s20 = bperm(i32, b2);
    float s21 = bperm(i32, b3);
    float s22 = bperm(i32, b0);
    float s23 = bperm(i32, b1);
    w[0] = qh ? s20 : b0;
    w[1] = qh ? s21 : b1;
    w[2] = qh ? b2 : s22;
    w[3] = qh ? b3 : s23;
}

// tick boundary: LDS release + barrier + compiler fence
#define SYNC() do { asm volatile("s_waitcnt lgkmcnt(0)" ::: "memory"); \
                    __builtin_amdgcn_s_barrier(); \
                    asm volatile("" ::: "memory"); } while (0)

extern "C" __global__ void __launch_bounds__(896, 1)
lstm_fused(const float* __restrict__ x,
           const float* __restrict__ Wih0, const float* __restrict__ Whh0,
           const float* __restrict__ bih0, const float* __restrict__ bhh0,
           const float* __restrict__ Wih1, const float* __restrict__ Whh1,
           const float* __restrict__ bih1, const float* __restrict__ bhh1,
           const float* __restrict__ Wih2, const float* __restrict__ Whh2,
           const float* __restrict__ bih2, const float* __restrict__ bhh2,
           const float* __restrict__ w0, const float* __restrict__ b0,
           const float* __restrict__ w1, const float* __restrict__ b1,
           const float* __restrict__ w2, const float* __restrict__ b2,
           const float* __restrict__ w3, const float* __restrict__ b3,
           const float* __restrict__ g0, const float* __restrict__ be0,
           const float* __restrict__ m0, const float* __restrict__ v0,
           const float* __restrict__ g1, const float* __restrict__ be1,
           const float* __restrict__ m1, const float* __restrict__ v1,
           const float* __restrict__ g2, const float* __restrict__ be2,
           const float* __restrict__ m2, const float* __restrict__ v2,
           float* __restrict__ out)
{
    __shared__ __align__(16) _Float16 in0[8 * SL0];
    __shared__ __align__(16) _Float16 in1[8 * SL1];
    __shared__ __align__(16) _Float16 in2[8 * SL1];
    __shared__ float fcA[BB * 64];
    __shared__ float fcB[BB * 64];
    __shared__ float fcW[54 * 65];
    __shared__ float fcP[5 * 64];

    const int tid  = threadIdx.x;
    const int wv   = tid >> 6;      // 0..13
    const int role = wv >> 2;       // 0=L2, 1=L1, 2=L0, 3=stager
    const int w4   = wv & 3;
    const int l    = tid & 63;
    const int q    = l >> 4;
    const int l15  = l & 15;
    const int u    = 16 * w4 + l15;
    const int b    = q;
    const int n0   = blockIdx.x * BB;

    for (int i = tid; i < 8 * SL0; i += 896) in0[i] = (_Float16)0.0f;
    for (int i = tid; i < 8 * SL1; i += 896) in1[i] = (_Float16)0.0f;
    for (int i = tid; i < 8 * SL1; i += 896) in2[i] = (_Float16)0.0f;

    // ---- weight B-fragments: one unit-slice per wave ----
    half8 wf[4][4];
    float bv[4];
    if (role == 2) {                 // layer 0 (3 kt used)
#pragma unroll
        for (int g = 0; g < 4; ++g) {
            const int row = 64 * g + u;
#pragma unroll
            for (int kt = 0; kt < 3; ++kt) {
                half8 h{};
#pragma unroll
                for (int j = 0; j < 8; ++j) {
                    const int k = 32 * kt + 8 * q + j;
                    float val = 0.0f;
                    if (k < 32) { if (k < FF) val = Wih0[row * FF + k]; }
                    else        { val = Whh0[row * HH + (k - 32)]; }
                    h[j] = (_Float16)val;
                }
                wf[g][kt] = h;
            }
            wf[g][3] = half8{};
            bv[g] = bih0[row] + bhh0[row];
        }
    } else if (role < 2) {            // 0 -> layer 2, 1 -> layer 1
        const float* Wih = role ? Wih1 : Wih2;
        const float* Whh = role ? Whh1 : Whh2;
        const float* bih = role ? bih1 : bih2;
        const float* bhh = role ? bhh1 : bhh2;
#pragma unroll
        for (int g = 0; g < 4; ++g) {
            const int row = 64 * g + u;
#pragma unroll
            for (int kt = 0; kt < 4; ++kt) {
                half8 h{};
#pragma unroll
                for (int j = 0; j < 8; ++j) {
                    const int k = 32 * kt + 8 * q + j;
                    h[j] = (_Float16)((k < 64) ? Wih[row * HH + k] : Whh[row * HH + (k - 64)]);
                }
                wf[g][kt] = h;
            }
            bv[g] = bih[row] + bhh[row];
        }
    }

    // ---- x staging lanes: waves 12-13, 88 items ----
    const int  st  = tid - 768;
    const bool xok = (role == 3) && (st >= 0) && (st < BB * FF);
    const int  xb  = xok ? (st / FF) : 0;
    const int  xf  = xok ? (st - xb * FF) : 0;
    const float* xp = x + ((size_t)(n0 + xb) * FF + xf) * TT;

    __syncthreads();                 // zero-init visible

    // pre-stage x(0) -> slot 0, x(1) -> slot 1
    if (xok) {
        in0[0 * SL0 + xb * S0 + xf] = (_Float16)xp[0];
        in0[1 * SL0 + xb * S0 + xf] = (_Float16)xp[1];
    }
    float xA = xok ? xp[2] : 0.f;    // x(tau+2) to write at tick tau=0
    float xB = xok ? xp[3] : 0.f;    // depth-2 prefetch

    __syncthreads();                 // pre-staged x visible

    // addressing
    const int fb    = (l15 & 3) * ((role == 2) ? S0 : S1) + q * 8; // A-frag base
    const int soff  = l15 >> 2;                                    // t'-subindex
    const int i16   = ((l ^ 16) << 2);                             // bperm idx
    const int i32   = ((l ^ 32) << 2);
    const bool qo   = (q & 1) != 0;
    const bool qh   = (q & 2) != 0;
    float c = 0.f;
    const float4v zz = {0.f, 0.f, 0.f, 0.f};
    float4v W0[4] = {zz, zz, zz, zz};
    float4v W1[4] = {zz, zz, zz, zz};
    float4v biasC[4];
#pragma unroll
    for (int g = 0; g < 4; ++g) biasC[g] = float4v{bv[g], bv[g], bv[g], bv[g]};

    // ============ main loop: 127*8 = 1016 ticks, 1 barrier each ============
    for (int k = 0; k < 127; ++k) {
#pragma unroll
        for (int s = 0; s < 8; ++s) {
            const int tau = 8 * k + s;
            SYNC();

            if (role == 3) {         // ===== stager: write x(tau+2) =====
                if (tau <= TT - 3) {
                    if (xok) in0[((s + 2) & 7) * SL0 + xb * S0 + xf] = (_Float16)xA;
                    xA = xB;
                    if (xok) {
                        int tn = tau + 4; if (tn > TT - 1) tn = TT - 1;
                        xB = xp[tn];
                    }
                }
            } else if (role == 2) {  // ===== L0: t = tau (R13-exact) =====
                if (tau <= TT - 1) {
                    const _Float16* rd = in0 + s * SL0;
                    half8 a0 = *(const half8*)(rd + fb);
                    half8 a1 = *(const half8*)(rd + fb + 32);
                    half8 a2 = *(const half8*)(rd + fb + 64);
                    float4v A[4];
#pragma unroll
                    for (int g = 0; g < 4; ++g)
                        A[g] = __builtin_amdgcn_mfma_f32_16x16x32_f16(a0, wf[g][0], biasC[g], 0, 0, 0);
#pragma unroll
                    for (int g = 0; g < 4; ++g)
                        A[g] = __builtin_amdgcn_mfma_f32_16x16x32_f16(a1, wf[g][1], A[g], 0, 0, 0);
#pragma unroll
                    for (int g = 0; g < 4; ++g)
                        A[g] = __builtin_amdgcn_mfma_f32_16x16x32_f16(a2, wf[g][2], A[g], 0, 0, 0);
                    float z[4];
#pragma unroll
                    for (int g = 0; g < 4; ++g) z[g] = sel4(A[g], q);
                    float h = gate_fused(z, c);
                    _Float16 hf = (_Float16)h;
                    in0[((s + 1) & 7) * SL0 + b * S0 + 32 + u] = hf; // rec -> slot tau+1
                    in1[s * SL1 + b * S1 + u]                  = hf; // fwd -> slot tau
                }
            } else if (role == 1) {  // ===== L1: t = tau-6 =====
                // ---- batched fwd (s==0 -> W0, s==4 -> W1) ----
                if (s == 0 || s == 4) {
                    if (tau >= 4 && tau <= TT) {         // t0 = tau-4 in [0,996]
                        const int sl = (s + 4 + soff) & 7; // (tau-4+soff)&7
                        const _Float16* fp = in1 + sl * SL1 + fb;
                        half8 fa0 = *(const half8*)(fp);
                        half8 fa1 = *(const half8*)(fp + 32);
                        float4v F[4];
#pragma unroll
                        for (int g = 0; g < 4; ++g)
                            F[g] = __builtin_amdgcn_mfma_f32_16x16x32_f16(fa0, wf[g][0], biasC[g], 0, 0, 0);
#pragma unroll
                        for (int g = 0; g < 4; ++g)
                            F[g] = __builtin_amdgcn_mfma_f32_16x16x32_f16(fa1, wf[g][1], F[g], 0, 0, 0);
#pragma unroll
                        for (int g = 0; g < 4; ++g) {
                            if (s == 0) transp4(W0[g], F[g], qo, qh, i16, i32);
                            else        transp4(W1[g], F[g], qo, qh, i16, i32);
                        }
                    }
                }
                // ---- rec + gates ----
                if (tau >= 6 && tau <= TT + 5) {
                    const _Float16* rr = in1 + ((s + 2) & 7) * SL1; // slot (tau-6)&7
                    half8 r2 = *(const half8*)(rr + fb + 64);
                    half8 r3 = *(const half8*)(rr + fb + 96);
                    float4v A[4];
#pragma unroll
                    for (int g = 0; g < 4; ++g)
                        A[g] = __builtin_amdgcn_mfma_f32_16x16x32_f16(r2, wf[g][2], zz, 0, 0, 0);
#pragma unroll
                    for (int g = 0; g < 4; ++g)
                        A[g] = __builtin_amdgcn_mfma_f32_16x16x32_f16(r3, wf[g][3], A[g], 0, 0, 0);
                    float z[4];
                    const int ri = (s + 2) & 3;
#pragma unroll
                    for (int g = 0; g < 4; ++g) {
                        const float fw = (s >= 2 && s <= 5) ? W0[g][ri] : W1[g][ri];
                        z[g] = sel4(A[g], q) + fw;
                    }
                    float h = gate_fused(z, c);
                    _Float16 hf = (_Float16)h;
                    in1[((s + 3) & 7) * SL1 + b * S1 + 64 + u] = hf; // rec: h1(t)->slot (t+1)&7
                    in2[((s + 2) & 7) * SL1 + b * S1 + u]      = hf; // fwd: h1(t)->slot t&7
                }
            } else {                 // ===== L2: t = tau-12 =====
                // ---- batched fwd (s==2 -> W0, s==6 -> W1) ----
                if (s == 2 || s == 6) {
                    if (tau >= 10 && tau <= TT + 6) {    // t0 = tau-10 in [0,996]
                        const int sl = (s + 6 + soff) & 7; // (tau-10+soff)&7
                        const _Float16* fp = in2 + sl * SL1 + fb;
                        half8 fa0 = *(const half8*)(fp);
                        half8 fa1 = *(const half8*)(fp + 32);
                        float4v F[4];
#pragma unroll
                        for (int g = 0; g < 4; ++g)
                            F[g] = __builtin_amdgcn_mfma_f32_16x16x32_f16(fa0, wf[g][0], biasC[g], 0, 0, 0);
#pragma unroll
                        for (int g = 0; g < 4; ++g)
                            F[g] = __builtin_amdgcn_mfma_f32_16x16x32_f16(fa1, wf[g][1], F[g], 0, 0, 0);
#pragma unroll
                        for (int g = 0; g < 4; ++g) {
                            if (s == 2) transp4(W0[g], F[g], qo, qh, i16, i32);
                            else        transp4(W1[g], F[g], qo, qh, i16, i32);
                        }
                    }
                }
                // ---- rec + gates ----
                if (tau >= 12 && tau <= TT + 11) {
                    const _Float16* rr = in2 + ((s + 4) & 7) * SL1; // slot (tau-12)&7
                    half8 r2 = *(const half8*)(rr + fb + 64);
                    half8 r3 = *(const half8*)(rr + fb + 96);
                    float4v A[4];
#pragma unroll
                    for (int g = 0; g < 4; ++g)
                        A[g] = __builtin_amdgcn_mfma_f32_16x16x32_f16(r2, wf[g][2], zz, 0, 0, 0);
#pragma unroll
                    for (int g = 0; g < 4; ++g)
                        A[g] = __builtin_amdgcn_mfma_f32_16x16x32_f16(r3, wf[g][3], A[g], 0, 0, 0);
                    float z[4];
                    const int ri = s & 3;
#pragma unroll
                    for (int g = 0; g < 4; ++g) {
                        const float fw = (s >= 4) ? W0[g][ri] : W1[g][ri];
                        z[g] = sel4(A[g], q) + fw;
                    }
                    float h = gate_fused(z, c);
                    if (tau != TT + 11) {
                        in2[((s + 5) & 7) * SL1 + b * S1 + 64 + u] = (_Float16)h; // h2(t)->slot (t+1)&7
                    } else {
                        fcA[b * 64 + u] = h;              // final h2(999), fp32
                    }
                }
            }
        }
    }

    __syncthreads();

    // ================= FC head (fp32) =================
    for (int i = tid; i < 54 * 64; i += 896) fcW[(i >> 6) * 65 + (i & 63)] = w0[i];
    for (int i = tid; i < 54; i += 896) {
        fcP[i] = b0[i]; fcP[64 + i] = g0[i]; fcP[128 + i] = be0[i];
        fcP[192 + i] = m0[i]; fcP[256 + i] = v0[i];
    }
    __syncthreads();
    for (int idx = tid; idx < BB * 54; idx += 896) {
        const int bb = idx / 54, j = idx - bb * 54;
        float s = fcP[j];
        for (int k = 0; k < 64; ++k) s += fcW[j * 65 + k] * fcA[bb * 64 + k];
        s = (s - fcP[192 + j]) * rsqrtf(fcP[256 + j] + 1e-5f) * fcP[64 + j] + fcP[128 + j];
        fcB[bb * 64 + j] = fmaxf(s, 0.0f);
    }
    __syncthreads();

    for (int i = tid; i < 44 * 54; i += 896) fcW[(i / 54) * 55 + (i % 54)] = w1[i];
    for (int i = tid; i < 44; i += 896) {
        fcP[i] = b1[i]; fcP[64 + i] = g1[i]; fcP[128 + i] = be1[i];
        fcP[192 + i] = m1[i]; fcP[256 + i] = v1[i];
    }
    __syncthreads();
    for (int idx = tid; idx < BB * 44; idx += 896) {
        const int bb = idx / 44, j = idx - bb * 44;
        float s = fcP[j];
        for (int k = 0; k < 54; ++k) s += fcW[j * 55 + k] * fcB[bb * 64 + k];
        s = (s - fcP[192 + j]) * rsqrtf(fcP[256 + j] + 1e-5f) * fcP[64 + j] + fcP[128 + j];
        fcA[bb * 64 + j] = fmaxf(s, 0.0f);
    }
    __syncthreads();

    for (int i = tid; i < 24 * 44; i += 896) fcW[(i / 44) * 45 + (i % 44)] = w2[i];
    for (int i = tid; i < 24; i += 896) {
        fcP[i] = b2[i]; fcP[64 + i] = g2[i]; fcP[128 + i] = be2[i];
        fcP[192 + i] = m2[i]; fcP[256 + i] = v2[i];
    }
    __syncthreads();
    for (int idx = tid; idx < BB * 24; idx += 896) {
        const int bb = idx / 24, j = idx - bb * 24;
        float s = fcP[j];
        for (int k = 0; k < 44; ++k) s += fcW[j * 45 + k] * fcA[bb * 64 + k];
        s = (s - fcP[192 + j]) * rsqrtf(fcP[256 + j] + 1e-5f) * fcP[64 + j] + fcP[128 + j];
        fcB[bb * 64 + j] = fmaxf(s, 0.0f);
    }
    __syncthreads();

    for (int i = tid; i < 4 * 24; i += 896) fcW[(i / 24) * 25 + (i % 24)] = w3[i];
    for (int i = tid; i < 4; i += 896) fcP[i] = b3[i];
    __syncthreads();
    for (int idx = tid; idx < BB * 4; idx += 896) {
        const int bb = idx / 4, j = idx - bb * 4;
        float s = fcP[j];
        for (int k = 0; k < 24; ++k) s += fcW[j * 25 + k] * fcB[bb * 64 + k];
        out[(size_t)(n0 + bb) * 4 + j] = s;
    }
}

extern "C" void kernel_launch(void* const* d_in, const int* in_sizes, int n_in,
                              void* d_out, int out_size, void* d_ws, size_t ws_size,
                              hipStream_t stream) {
    const float* p[33];
    for (int i = 0; i < 33; ++i) p[i] = (const float*)d_in[i];
    lstm_fused<<<NBLK, 896, 0, stream>>>(
        p[0],
        p[1], p[2], p[3], p[4],
        p[5], p[6], p[7], p[8],
        p[9], p[10], p[11], p[12],
        p[13], p[14], p[15], p[16], p[17], p[18], p[19], p[20],
        p[21], p[22], p[23], p[24],
        p[25], p[26], p[27], p[28],
        p[29], p[30], p[31], p[32],
        (float*)d_out);
}